// Round 7
// baseline (118.933 us; speedup 1.0000x reference)
//
#include <hip/hip_runtime.h>

// GCN 2-layer for MI355X — fully bucket-major edge sort with XCD-local
// scatter, then contiguous-read LDS aggregation.
// Round-6 lesson: agg kernels were latency-bound on 128 scattered 32B
// fragment reads per block. Now packed[] is globally sorted by bucket
// (region order: bucket-major, x=XCD-major within bucket), so every agg
// block reads ONE contiguous coalesced slice. The sort's scattered 4B
// stores stay XCD-local (super-partition x = blockIdx&7), so lines
// write-combine in the owning L2 (round-4's cross-XCD 6x write-amp fix).
//
// packed record: src (bits 0..16) | local_dst (bits 17..24)

#define NPB     256     // nodes per bucket
#define NBSHIFT 8
#define NBLK    1024    // hist/scatter blocks (128 per XCD partition)
#define HBS     256     // hist/scatter threads
#define ABS     256     // agg block threads (== NPB)

// block -> edge range; super-partition x = b&7 (empirically the XCD).
__device__ __forceinline__ void edge_range(int b, int E, int* lo, int* cnt) {
    int x = b & 7, sub = b >> 3;
    int Ex  = (E + 7) >> 3;
    int epx = (Ex + (NBLK / 8) - 1) / (NBLK / 8);
    int l = x * Ex + sub * epx;
    int h = min(l + epx, min((x + 1) * Ex, E));
    *lo = l; *cnt = max(0, h - l);
}

// Per-block bucket histogram, block-major (coalesced flush).
__global__ __launch_bounds__(HBS) void k_hist(
    const int* __restrict__ dst, int E, int nbuck, int* __restrict__ bhist)
{
    __shared__ int h[512];
    const int b = blockIdx.x, t = threadIdx.x;
    for (int k = t; k < nbuck; k += HBS) h[k] = 0;
    __syncthreads();
    int lo, cnt; edge_range(b, E, &lo, &cnt);
    for (int i = t; i < cnt; i += HBS)
        atomicAdd(&h[dst[lo + i] >> NBSHIFT], 1);
    __syncthreads();
    for (int k = t; k < nbuck; k += HBS)
        bhist[(size_t)b * nbuck + k] = h[k];
}

// One block per bucket k: exclusive scan of the NBLK block-counts in
// x-major order (region order within the bucket). In place. Also bucket sum.
__global__ __launch_bounds__(NBLK) void k_colscan(
    int* __restrict__ bhist, int nbuck, int* __restrict__ bsum)
{
    __shared__ int s[NBLK];
    const int k = blockIdx.x, t = threadIdx.x;
    // seq index t = x*(NBLK/8) + sub  ->  block b = sub*8 + x
    const int b = ((t & (NBLK / 8 - 1)) << 3) | (t >> 7);   // NBLK=1024
    int v = bhist[(size_t)b * nbuck + k];
    s[t] = v;
    for (int off = 1; off < NBLK; off <<= 1) {
        __syncthreads();
        int a = (t >= off) ? s[t - off] : 0;
        __syncthreads();
        s[t] += a;
    }
    __syncthreads();
    bhist[(size_t)b * nbuck + k] = s[t] - v;   // exclusive, in place
    if (t == NBLK - 1) bsum[k] = s[t];
}

// Single block: exclusive scan of bucket sums -> bstart.
__global__ __launch_bounds__(512) void k_base(
    const int* __restrict__ bsum, int nbuck, int* __restrict__ bstart, int E)
{
    __shared__ int s[512];
    const int t = threadIdx.x;
    int v = (t < nbuck) ? bsum[t] : 0;
    s[t] = v;
    for (int off = 1; off < 512; off <<= 1) {
        __syncthreads();
        int a = (t >= off) ? s[t - off] : 0;
        __syncthreads();
        s[t] += a;
    }
    if (t < nbuck) bstart[t] = s[t] - v;
    if (t == 0) bstart[nbuck] = E;
}

// Scatter edges into bucket-major packed[]; stores land in this XCD's
// exclusive (x,k) sub-regions -> L2 write-combining, no cross-XCD bounce.
__global__ __launch_bounds__(HBS) void k_scatter(
    const int* __restrict__ src, const int* __restrict__ dst, int E, int nbuck,
    const int* __restrict__ bhist, const int* __restrict__ bstart,
    unsigned* __restrict__ packed)
{
    __shared__ int lcur[512];
    const int b = blockIdx.x, t = threadIdx.x;
    for (int k = t; k < nbuck; k += HBS)
        lcur[k] = bstart[k] + bhist[(size_t)b * nbuck + k];
    __syncthreads();
    int lo, cnt; edge_range(b, E, &lo, &cnt);
    for (int i = t; i < cnt; i += HBS) {
        int d = dst[lo + i];
        int s = src[lo + i];
        int p = atomicAdd(&lcur[d >> NBSHIFT], 1);
        packed[p] = (unsigned)s | ((unsigned)(d & (NPB - 1)) << 17);
    }
}

// ---- aggregation: block (k,s) reads a contiguous slice of bucket k's run.

__global__ __launch_bounds__(ABS) void k_deg(
    const unsigned* __restrict__ packed, const int* __restrict__ bstart,
    int nbuck, int S, int* __restrict__ pc)
{
    __shared__ int cnt[NPB];
    const int k = blockIdx.x % nbuck, sp = blockIdx.x / nbuck, t = threadIdx.x;
    cnt[t] = 0;
    __syncthreads();
    int base = bstart[k], len = bstart[k + 1] - base;
    int lo = base + (int)((long long)len * sp / S);
    int hi = base + (int)((long long)len * (sp + 1) / S);
    for (int i = lo + t; i < hi; i += ABS)
        atomicAdd(&cnt[packed[i] >> 17], 1);
    __syncthreads();
    pc[((size_t)sp * nbuck + k) * NPB + t] = cnt[t];
}

__global__ __launch_bounds__(ABS) void k_agg1(
    const unsigned* __restrict__ packed, const int* __restrict__ bstart,
    const float* __restrict__ p1, int nbuck, int S, float* __restrict__ pa1)
{
    __shared__ float acc[NPB];
    const int k = blockIdx.x % nbuck, sp = blockIdx.x / nbuck, t = threadIdx.x;
    acc[t] = 0.f;
    __syncthreads();
    int base = bstart[k], len = bstart[k + 1] - base;
    int lo = base + (int)((long long)len * sp / S);
    int hi = base + (int)((long long)len * (sp + 1) / S);
    for (int i = lo + t; i < hi; i += ABS) {
        unsigned u = packed[i];
        atomicAdd(&acc[u >> 17], p1[u & 0x1FFFFu]);
    }
    __syncthreads();
    pa1[((size_t)sp * nbuck + k) * NPB + t] = acc[t];
}

__global__ __launch_bounds__(ABS) void k_agg2(
    const unsigned* __restrict__ packed, const int* __restrict__ bstart,
    const float2* __restrict__ p2, int nbuck, int S, float2* __restrict__ pa2)
{
    __shared__ float a0[NPB], a1[NPB];
    const int k = blockIdx.x % nbuck, sp = blockIdx.x / nbuck, t = threadIdx.x;
    a0[t] = 0.f; a1[t] = 0.f;
    __syncthreads();
    int base = bstart[k], len = bstart[k + 1] - base;
    int lo = base + (int)((long long)len * sp / S);
    int hi = base + (int)((long long)len * (sp + 1) / S);
    for (int i = lo + t; i < hi; i += ABS) {
        unsigned u = packed[i];
        float2 vv = p2[u & 0x1FFFFu];
        int d = u >> 17;
        atomicAdd(&a0[d], vv.x);
        atomicAdd(&a1[d], vv.y);
    }
    __syncthreads();
    pa2[((size_t)sp * nbuck + k) * NPB + t] = make_float2(a0[t], a1[t]);
}

// ---- node epilogues (reduce S partials + fused pointwise math).

__global__ void k_dis(const int* __restrict__ pc, const float* __restrict__ x,
                      int nbuck, int S, int n,
                      float* __restrict__ dis, float* __restrict__ p1) {
    int d = blockIdx.x * blockDim.x + threadIdx.x;
    if (d >= n) return;
    size_t nround = (size_t)nbuck * NPB;
    int c = 0;
    for (int s = 0; s < S; ++s) c += pc[s * nround + d];
    float r = rsqrtf((float)(c + 1));          // +1 self-loop
    dis[d] = r;
    p1[d]  = x[d] * r;
}

__global__ void k_node(const float* __restrict__ pa1,
                       const float* __restrict__ dis, const float* __restrict__ p1,
                       const float* __restrict__ W1, const float* __restrict__ b1,
                       const float* __restrict__ W2,
                       int nbuck, int S, int n, float2* __restrict__ p2) {
    int d = blockIdx.x * blockDim.x + threadIdx.x;
    if (d >= n) return;
    size_t nround = (size_t)nbuck * NPB;
    float a = 0.f;
    for (int s = 0; s < S; ++s) a += pa1[s * nround + d];
    float r   = dis[d];
    float agg = r * (a + p1[d]);               // + self-loop
    float c0 = 0.f, c1 = 0.f;
#pragma unroll
    for (int j = 0; j < 16; ++j) {
        float h = fmaxf(fmaf(agg, W1[j], b1[j]), 0.f);
        c0 = fmaf(h, W2[2 * j],     c0);
        c1 = fmaf(h, W2[2 * j + 1], c1);
    }
    p2[d] = make_float2(c0 * r, c1 * r);       // prescaled by dis[src]
}

__global__ void k_final(const float2* __restrict__ pa2,
                        const float* __restrict__ dis, const float2* __restrict__ p2,
                        const float* __restrict__ b2,
                        int nbuck, int S, int n, float2* __restrict__ out) {
    int d = blockIdx.x * blockDim.x + threadIdx.x;
    if (d >= n) return;
    size_t nround = (size_t)nbuck * NPB;
    float a0 = 0.f, a1 = 0.f;
    for (int s = 0; s < S; ++s) {
        float2 v = pa2[s * nround + d];
        a0 += v.x; a1 += v.y;
    }
    float r = dis[d];
    float2 self = p2[d];
    float o0 = r * (a0 + self.x) + b2[0];
    float o1 = r * (a1 + self.y) + b2[1];
    float m  = fmaxf(o0, o1);
    float ls = m + logf(expf(o0 - m) + expf(o1 - m));
    out[d] = make_float2(o0 - ls, o1 - ls);
}

extern "C" void kernel_launch(void* const* d_in, const int* in_sizes, int n_in,
                              void* d_out, int out_size, void* d_ws, size_t ws_size,
                              hipStream_t stream) {
    const float* x  = (const float*)d_in[0];
    const int*   ei = (const int*)d_in[1];     // int32 [2, E]
    const float* W1 = (const float*)d_in[2];
    const float* b1 = (const float*)d_in[3];
    const float* W2 = (const float*)d_in[4];
    const float* b2 = (const float*)d_in[5];

    const int n = in_sizes[0];                 // 100000
    const int E = in_sizes[1] / 2;             // 3200000
    const int* src = ei;
    const int* dst = ei + E;

    const int nbuck = (n + NPB - 1) >> NBSHIFT;        // 391
    const size_t nround = (size_t)nbuck * NPB;

    // Split factor by workspace capacity.
    auto need = [&](int S_) -> size_t {
        return (size_t)NBLK * nbuck * 4            // bhist (scanned in place)
             + (size_t)(2 * nbuck + 2) * 4         // bsum + bstart
             + (size_t)E * 4                       // packed
             + (size_t)S_ * nround * 16            // pc + pa1 + pa2
             + (size_t)n * 16 + 256;               // dis + p1 + p2 + slack
    };
    int S = 8;
    while (S > 1 && need(S) > ws_size) S >>= 1;

    // Workspace layout.
    char* ws = (char*)d_ws;
    size_t off = 0;
    auto take = [&](size_t bytes) { char* p = ws + off; off += (bytes + 7) & ~(size_t)7; return p; };
    int*      bhist  = (int*)take((size_t)NBLK * nbuck * 4);
    int*      bsum   = (int*)take((size_t)nbuck * 4);
    int*      bstart = (int*)take((size_t)(nbuck + 1) * 4);
    unsigned* packed = (unsigned*)take((size_t)E * 4);
    int*      pc     = (int*)take((size_t)S * nround * 4);
    float*    pa1    = (float*)take((size_t)S * nround * 4);
    float2*   pa2    = (float2*)take((size_t)S * nround * 8);
    float*    dis    = (float*)take((size_t)n * 4);
    float*    p1     = (float*)take((size_t)n * 4);
    float2*   p2     = (float2*)take((size_t)n * 8);

    const int gridAgg = nbuck * S;
    const int gridN   = (n + 255) / 256;

    k_hist   <<<NBLK, HBS, 0, stream>>>(dst, E, nbuck, bhist);
    k_colscan<<<nbuck, NBLK, 0, stream>>>(bhist, nbuck, bsum);
    k_base   <<<1, 512, 0, stream>>>(bsum, nbuck, bstart, E);
    k_scatter<<<NBLK, HBS, 0, stream>>>(src, dst, E, nbuck, bhist, bstart, packed);
    k_deg    <<<gridAgg, ABS, 0, stream>>>(packed, bstart, nbuck, S, pc);
    k_dis    <<<gridN, 256, 0, stream>>>(pc, x, nbuck, S, n, dis, p1);
    k_agg1   <<<gridAgg, ABS, 0, stream>>>(packed, bstart, p1, nbuck, S, pa1);
    k_node   <<<gridN, 256, 0, stream>>>(pa1, dis, p1, W1, b1, W2, nbuck, S, n, p2);
    k_agg2   <<<gridAgg, ABS, 0, stream>>>(packed, bstart, p2, nbuck, S, pa2);
    k_final  <<<gridN, 256, 0, stream>>>(pa2, dis, p2, b2, nbuck, S, n, (float2*)d_out);
}

// Round 8
// 111.434 us; speedup vs baseline: 1.0673x; 1.0673x over previous
//
#include <hip/hip_runtime.h>

// GCN 2-layer for MI355X — two-level counting sort to per-node CSR, then
// atomic-free register-reduction aggregation.
// Rounds 5-7 showed agg time (40 us) is invariant to packed[] layout:
// the per-edge random gather + LDS atomics are the cost. This version
// removes ALL aggregation atomics and all partial arrays: CSR once
// (4 LDS atomics/edge), then each node is reduced by a 4-lane group in
// registers, with the node MLP / log-softmax fused into the agg kernels.
//
// record: src (bits 0..16) | local_dst (bits 17..23), NPB=128

#define NPB    128      // nodes per bucket
#define NBSH   7
#define NPART  256      // partition blocks (fragments of ~16 recs = 64 B)
#define PBS    1024     // k_part threads
#define EPT    13       // edges/thread in k_part (epb <= 13312)
#define CAP    5120     // max records per bucket (mean 4096, sd 64; +16 sd)
#define CBS    512      // k_csr threads
#define ABS    512      // agg threads
#define LPN    4        // lanes per node in agg

// ---- level 1: block-major bucket sort (one kernel, no global scan) ----
__global__ __launch_bounds__(PBS) void k_part(
    const int* __restrict__ src, const int* __restrict__ dst,
    int E, int epb, int nbuck,
    int* __restrict__ offT, unsigned* __restrict__ packed)
{
    __shared__ int s_scan[PBS];
    __shared__ unsigned stage[PBS * EPT];
    const int b = blockIdx.x, t = threadIdx.x;
    const int lo = b * epb;
    int blockEdges = min(epb, E - lo); if (blockEdges < 0) blockEdges = 0;

    unsigned rec[EPT]; int bkt[EPT];
    s_scan[t] = 0;
    __syncthreads();
#pragma unroll
    for (int it = 0; it < EPT; ++it) {
        int idx = it * PBS + t;
        bkt[it] = -1; rec[it] = 0;
        if (idx < blockEdges) {
            int d = dst[lo + idx], s = src[lo + idx];
            rec[it] = (unsigned)s | ((unsigned)(d & (NPB - 1)) << 17);
            bkt[it] = d >> NBSH;
            atomicAdd(&s_scan[bkt[it]], 1);
        }
    }
    __syncthreads();
    int v = s_scan[t];
    for (int off = 1; off < PBS; off <<= 1) {
        __syncthreads();
        int a = (t >= off) ? s_scan[t - off] : 0;
        __syncthreads();
        s_scan[t] += a;
    }
    __syncthreads();
    int excl = s_scan[t] - v;
    __syncthreads();
    s_scan[t] = excl;                          // reuse as cursors
    if (t < nbuck) offT[(size_t)b * nbuck + t] = excl;
    __syncthreads();
#pragma unroll
    for (int it = 0; it < EPT; ++it)
        if (bkt[it] >= 0) {
            int pos = atomicAdd(&s_scan[bkt[it]], 1);
            stage[pos] = rec[it];
        }
    __syncthreads();
    for (int i = t; i < blockEdges; i += PBS)
        packed[(size_t)lo + i] = stage[i];
}

// ---- level 2: per-bucket node-level sort -> CSR + deg/dis/p1 fused ----
__global__ __launch_bounds__(CBS) void k_csr(
    const unsigned* __restrict__ packed, const int* __restrict__ offT,
    const float* __restrict__ x,
    int E, int epb, int nbuck, int n,
    unsigned* __restrict__ sorted, int* __restrict__ nstart, int* __restrict__ nend,
    float* __restrict__ dis, float* __restrict__ p1)
{
    __shared__ unsigned raw[CAP];
    __shared__ int offs[NPART], flen[NPART], fbase[NPART];
    __shared__ int cnt[NPB], cur[NPB];
    const int k = blockIdx.x, t = threadIdx.x;

    if (t < NPART) {
        int o = offT[(size_t)t * nbuck + k];
        int e = (k + 1 < nbuck) ? offT[(size_t)t * nbuck + k + 1]
                                : max(0, min(epb, E - t * epb));
        offs[t] = o; flen[t] = e - o;
        fbase[t] = e - o;
    }
    if (t < NPB) cnt[t] = 0;
    __syncthreads();
    // exclusive scan of fragment lengths -> fbase
    for (int off = 1; off < NPART; off <<= 1) {
        __syncthreads();
        int a = (t >= off && t < NPART) ? fbase[t - off] : 0;
        __syncthreads();
        if (t < NPART) fbase[t] += a;
    }
    __syncthreads();
    int bsize = min(fbase[NPART - 1], CAP);
    __syncthreads();
    if (t < NPART) fbase[t] -= flen[t];
    __syncthreads();
    // gather fragments into raw[] (2 lanes per fragment)
    {
        int f = t >> 1, l = t & 1;
        const unsigned* pp = packed + (size_t)f * epb + offs[f];
        int base = fbase[f], len = flen[f];
        for (int i = l; i < len; i += 2) {
            int p = base + i;
            if (p < CAP) raw[p] = pp[i];
        }
    }
    __syncthreads();
    // node-level count
    for (int i = t; i < bsize; i += CBS)
        atomicAdd(&cnt[raw[i] >> 17], 1);
    __syncthreads();
    // exclusive scan of cnt (in cur), keep cnt = deg
    if (t < NPB) cur[t] = cnt[t];
    for (int off = 1; off < NPB; off <<= 1) {
        __syncthreads();
        int a = (t >= off && t < NPB) ? cur[t - off] : 0;
        __syncthreads();
        if (t < NPB) cur[t] += a;
    }
    __syncthreads();
    if (t < NPB) {
        int deg = cnt[t];
        int excl = cur[t] - deg;
        cur[t] = excl;                         // cursor for scatter
        int d = k * NPB + t;
        if (d < n) {
            int st = k * CAP + excl;
            nstart[d] = st;
            nend[d]   = min(st + deg, (k + 1) * CAP);
            float r = rsqrtf((float)(deg + 1)); // +1 self-loop
            dis[d] = r;
            p1[d]  = x[d] * r;
        }
    }
    __syncthreads();
    // scatter into node-sorted order (XCD-local contiguous region)
    for (int i = t; i < bsize; i += CBS) {
        unsigned u = raw[i];
        int pos = k * CAP + atomicAdd(&cur[u >> 17], 1);
        sorted[pos] = u;
    }
}

// ---- layer 1: atomic-free segment reduce + fused MLP -> p2 ----
__global__ __launch_bounds__(ABS) void k_agg1(
    const unsigned* __restrict__ sorted,
    const int* __restrict__ nstart, const int* __restrict__ nend,
    const float* __restrict__ dis, const float* __restrict__ p1,
    const float* __restrict__ W1, const float* __restrict__ b1,
    const float* __restrict__ W2, int n, float2* __restrict__ p2)
{
    int gid = blockIdx.x * ABS + threadIdx.x;
    int d = gid >> 2, lane = gid & (LPN - 1);
    if (d >= n) return;
    int s0 = nstart[d], e0 = nend[d];
    float acc = 0.f;
    for (int i = s0 + lane; i < e0; i += LPN) {
        int s = sorted[i] & 0x1FFFF;
        acc += __builtin_nontemporal_load(&p1[s]);
    }
    acc += __shfl_xor(acc, 1);
    acc += __shfl_xor(acc, 2);
    if (lane == 0) {
        float r   = dis[d];
        float agg = r * (acc + p1[d]);          // + self-loop
        float c0 = 0.f, c1 = 0.f;
#pragma unroll
        for (int j = 0; j < 16; ++j) {
            float h = fmaxf(fmaf(agg, W1[j], b1[j]), 0.f);
            c0 = fmaf(h, W2[2 * j],     c0);
            c1 = fmaf(h, W2[2 * j + 1], c1);
        }
        p2[d] = make_float2(c0 * r, c1 * r);    // prescaled by dis[src]
    }
}

// ---- layer 2: atomic-free segment reduce + fused log-softmax -> out ----
__global__ __launch_bounds__(ABS) void k_agg2(
    const unsigned* __restrict__ sorted,
    const int* __restrict__ nstart, const int* __restrict__ nend,
    const float* __restrict__ dis, const float2* __restrict__ p2,
    const float* __restrict__ b2, int n, float2* __restrict__ out)
{
    int gid = blockIdx.x * ABS + threadIdx.x;
    int d = gid >> 2, lane = gid & (LPN - 1);
    if (d >= n) return;
    int s0 = nstart[d], e0 = nend[d];
    const double* p2d = (const double*)p2;
    float c0 = 0.f, c1 = 0.f;
    for (int i = s0 + lane; i < e0; i += LPN) {
        int s = sorted[i] & 0x1FFFF;
        double dv = __builtin_nontemporal_load(&p2d[s]);
        float2 v = *(float2*)&dv;
        c0 += v.x; c1 += v.y;
    }
    c0 += __shfl_xor(c0, 1);  c0 += __shfl_xor(c0, 2);
    c1 += __shfl_xor(c1, 1);  c1 += __shfl_xor(c1, 2);
    if (lane == 0) {
        float r = dis[d];
        float2 self = p2[d];
        float o0 = r * (c0 + self.x) + b2[0];
        float o1 = r * (c1 + self.y) + b2[1];
        float m  = fmaxf(o0, o1);
        float ls = m + logf(expf(o0 - m) + expf(o1 - m));
        out[d] = make_float2(o0 - ls, o1 - ls);
    }
}

extern "C" void kernel_launch(void* const* d_in, const int* in_sizes, int n_in,
                              void* d_out, int out_size, void* d_ws, size_t ws_size,
                              hipStream_t stream) {
    const float* x  = (const float*)d_in[0];
    const int*   ei = (const int*)d_in[1];     // int32 [2, E]
    const float* W1 = (const float*)d_in[2];
    const float* b1 = (const float*)d_in[3];
    const float* W2 = (const float*)d_in[4];
    const float* b2 = (const float*)d_in[5];

    const int n = in_sizes[0];                 // 100000
    const int E = in_sizes[1] / 2;             // 3200000
    const int* src = ei;
    const int* dst = ei + E;

    const int nbuck = (n + NPB - 1) >> NBSH;   // 782 (<= PBS for the scan)
    const int epb   = (E + NPART - 1) / NPART; // 12500 (<= PBS*EPT)

    // Workspace layout (~32 MB).
    char* ws = (char*)d_ws;
    size_t off = 0;
    auto take = [&](size_t bytes) { char* p = ws + off; off += (bytes + 7) & ~(size_t)7; return p; };
    int*      offT   = (int*)take((size_t)NPART * nbuck * 4);     // 0.8 MB
    unsigned* packed = (unsigned*)take((size_t)E * 4);            // 12.8 MB
    unsigned* sorted = (unsigned*)take((size_t)nbuck * CAP * 4);  // 16 MB
    int*      nstart = (int*)take((size_t)n * 4);
    int*      nend   = (int*)take((size_t)n * 4);
    float*    dis    = (float*)take((size_t)n * 4);
    float*    p1     = (float*)take((size_t)n * 4);
    float2*   p2     = (float2*)take((size_t)n * 8);

    const int gridAgg = ((size_t)n * LPN + ABS - 1) / ABS;        // 782

    k_part<<<NPART, PBS, 0, stream>>>(src, dst, E, epb, nbuck, offT, packed);
    k_csr <<<nbuck, CBS, 0, stream>>>(packed, offT, x, E, epb, nbuck, n,
                                      sorted, nstart, nend, dis, p1);
    k_agg1<<<gridAgg, ABS, 0, stream>>>(sorted, nstart, nend, dis, p1,
                                        W1, b1, W2, n, p2);
    k_agg2<<<gridAgg, ABS, 0, stream>>>(sorted, nstart, nend, dis, p2,
                                        b2, n, (float2*)d_out);
}

// Round 9
// 109.563 us; speedup vs baseline: 1.0855x; 1.0171x over previous
//
#include <hip/hip_runtime.h>

// GCN 2-layer for MI355X — two-level counting sort to per-node CSR, then
// atomic-free register-reduction aggregation.
// Round-9 change (single-variable): k_csr only — CBS 512->1024 (32 waves/CU),
// fragment gather switched to 16-contiguous-lanes-per-fragment (coalesced
// 64 B reads, ~1-2 iters vs 8 dependent strided iters). k_part and the agg
// kernels are byte-identical to round 8 to isolate the delta.
//
// record: src (bits 0..16) | local_dst (bits 17..23), NPB=128

#define NPB    128      // nodes per bucket
#define NBSH   7
#define NPART  256      // partition blocks (fragments avg ~16 recs = 64 B)
#define PBS    1024     // k_part threads
#define EPT    13       // edges/thread in k_part (epb <= 13312)
#define CAP    5120     // max records per bucket (mean 4092, sd 64; +16 sd)
#define CBS    1024     // k_csr threads
#define ABS    512      // agg threads
#define LPN    4        // lanes per node in agg

// ---- level 1: block-major bucket sort (one kernel, no global scan) ----
__global__ __launch_bounds__(PBS) void k_part(
    const int* __restrict__ src, const int* __restrict__ dst,
    int E, int epb, int nbuck,
    int* __restrict__ offT, unsigned* __restrict__ packed)
{
    __shared__ int s_scan[PBS];
    __shared__ unsigned stage[PBS * EPT];
    const int b = blockIdx.x, t = threadIdx.x;
    const int lo = b * epb;
    int blockEdges = min(epb, E - lo); if (blockEdges < 0) blockEdges = 0;

    unsigned rec[EPT]; int bkt[EPT];
    s_scan[t] = 0;
    __syncthreads();
#pragma unroll
    for (int it = 0; it < EPT; ++it) {
        int idx = it * PBS + t;
        bkt[it] = -1; rec[it] = 0;
        if (idx < blockEdges) {
            int d = dst[lo + idx], s = src[lo + idx];
            rec[it] = (unsigned)s | ((unsigned)(d & (NPB - 1)) << 17);
            bkt[it] = d >> NBSH;
            atomicAdd(&s_scan[bkt[it]], 1);
        }
    }
    __syncthreads();
    int v = s_scan[t];
    for (int off = 1; off < PBS; off <<= 1) {
        __syncthreads();
        int a = (t >= off) ? s_scan[t - off] : 0;
        __syncthreads();
        s_scan[t] += a;
    }
    __syncthreads();
    int excl = s_scan[t] - v;
    __syncthreads();
    s_scan[t] = excl;                          // reuse as cursors
    if (t < nbuck) offT[(size_t)b * nbuck + t] = excl;
    __syncthreads();
#pragma unroll
    for (int it = 0; it < EPT; ++it)
        if (bkt[it] >= 0) {
            int pos = atomicAdd(&s_scan[bkt[it]], 1);
            stage[pos] = rec[it];
        }
    __syncthreads();
    for (int i = t; i < blockEdges; i += PBS)
        packed[(size_t)lo + i] = stage[i];
}

// ---- level 2: per-bucket node-level sort -> CSR + deg/dis/p1 fused ----
__global__ __launch_bounds__(CBS) void k_csr(
    const unsigned* __restrict__ packed, const int* __restrict__ offT,
    const float* __restrict__ x,
    int E, int epb, int nbuck, int n,
    unsigned* __restrict__ sorted, int* __restrict__ nstart, int* __restrict__ nend,
    float* __restrict__ dis, float* __restrict__ p1)
{
    __shared__ unsigned raw[CAP];
    __shared__ int offs[NPART], flen[NPART], fbase[NPART];
    __shared__ int cnt[NPB], cur[NPB];
    const int k = blockIdx.x, t = threadIdx.x;

    if (t < NPART) {
        int o = offT[(size_t)t * nbuck + k];
        int e = (k + 1 < nbuck) ? offT[(size_t)t * nbuck + k + 1]
                                : max(0, min(epb, E - t * epb));
        offs[t] = o; flen[t] = e - o;
        fbase[t] = e - o;
    }
    if (t < NPB) cnt[t] = 0;
    __syncthreads();
    // exclusive scan of fragment lengths -> fbase
    for (int off = 1; off < NPART; off <<= 1) {
        __syncthreads();
        int a = (t >= off && t < NPART) ? fbase[t - off] : 0;
        __syncthreads();
        if (t < NPART) fbase[t] += a;
    }
    __syncthreads();
    int bsize = min(fbase[NPART - 1], CAP);
    __syncthreads();
    if (t < NPART) fbase[t] -= flen[t];
    __syncthreads();
    // gather fragments into raw[]: 16 contiguous lanes per fragment
    // (64 B coalesced), 4 passes of 64 fragments each.
    for (int fb = 0; fb < NPART; fb += (CBS >> 4)) {
        int f = fb + (t >> 4);
        if (f < NPART) {
            const unsigned* pp = packed + (size_t)f * epb + offs[f];
            int base = fbase[f], len = flen[f];
            for (int i = (t & 15); i < len; i += 16) {
                int p = base + i;
                if (p < CAP) raw[p] = pp[i];
            }
        }
    }
    __syncthreads();
    // node-level count (4 iters/thread at CBS=1024)
    for (int i = t; i < bsize; i += CBS)
        atomicAdd(&cnt[raw[i] >> 17], 1);
    __syncthreads();
    // exclusive scan of cnt (in cur), keep cnt = deg
    if (t < NPB) cur[t] = cnt[t];
    for (int off = 1; off < NPB; off <<= 1) {
        __syncthreads();
        int a = (t >= off && t < NPB) ? cur[t - off] : 0;
        __syncthreads();
        if (t < NPB) cur[t] += a;
    }
    __syncthreads();
    if (t < NPB) {
        int deg = cnt[t];
        int excl = cur[t] - deg;
        cur[t] = excl;                         // cursor for scatter
        int d = k * NPB + t;
        if (d < n) {
            int st = k * CAP + excl;
            nstart[d] = st;
            nend[d]   = min(st + deg, (k + 1) * CAP);
            float r = rsqrtf((float)(deg + 1)); // +1 self-loop
            dis[d] = r;
            p1[d]  = x[d] * r;
        }
    }
    __syncthreads();
    // scatter into node-sorted order
    for (int i = t; i < bsize; i += CBS) {
        unsigned u = raw[i];
        int pos = k * CAP + atomicAdd(&cur[u >> 17], 1);
        sorted[pos] = u;
    }
}

// ---- layer 1: atomic-free segment reduce + fused MLP -> p2 ----
__global__ __launch_bounds__(ABS) void k_agg1(
    const unsigned* __restrict__ sorted,
    const int* __restrict__ nstart, const int* __restrict__ nend,
    const float* __restrict__ dis, const float* __restrict__ p1,
    const float* __restrict__ W1, const float* __restrict__ b1,
    const float* __restrict__ W2, int n, float2* __restrict__ p2)
{
    int gid = blockIdx.x * ABS + threadIdx.x;
    int d = gid >> 2, lane = gid & (LPN - 1);
    if (d >= n) return;
    int s0 = nstart[d], e0 = nend[d];
    float acc = 0.f;
    for (int i = s0 + lane; i < e0; i += LPN) {
        int s = sorted[i] & 0x1FFFF;
        acc += __builtin_nontemporal_load(&p1[s]);
    }
    acc += __shfl_xor(acc, 1);
    acc += __shfl_xor(acc, 2);
    if (lane == 0) {
        float r   = dis[d];
        float agg = r * (acc + p1[d]);          // + self-loop
        float c0 = 0.f, c1 = 0.f;
#pragma unroll
        for (int j = 0; j < 16; ++j) {
            float h = fmaxf(fmaf(agg, W1[j], b1[j]), 0.f);
            c0 = fmaf(h, W2[2 * j],     c0);
            c1 = fmaf(h, W2[2 * j + 1], c1);
        }
        p2[d] = make_float2(c0 * r, c1 * r);    // prescaled by dis[src]
    }
}

// ---- layer 2: atomic-free segment reduce + fused log-softmax -> out ----
__global__ __launch_bounds__(ABS) void k_agg2(
    const unsigned* __restrict__ sorted,
    const int* __restrict__ nstart, const int* __restrict__ nend,
    const float* __restrict__ dis, const float2* __restrict__ p2,
    const float* __restrict__ b2, int n, float2* __restrict__ out)
{
    int gid = blockIdx.x * ABS + threadIdx.x;
    int d = gid >> 2, lane = gid & (LPN - 1);
    if (d >= n) return;
    int s0 = nstart[d], e0 = nend[d];
    const double* p2d = (const double*)p2;
    float c0 = 0.f, c1 = 0.f;
    for (int i = s0 + lane; i < e0; i += LPN) {
        int s = sorted[i] & 0x1FFFF;
        double dv = __builtin_nontemporal_load(&p2d[s]);
        float2 v = *(float2*)&dv;
        c0 += v.x; c1 += v.y;
    }
    c0 += __shfl_xor(c0, 1);  c0 += __shfl_xor(c0, 2);
    c1 += __shfl_xor(c1, 1);  c1 += __shfl_xor(c1, 2);
    if (lane == 0) {
        float r = dis[d];
        float2 self = p2[d];
        float o0 = r * (c0 + self.x) + b2[0];
        float o1 = r * (c1 + self.y) + b2[1];
        float m  = fmaxf(o0, o1);
        float ls = m + logf(expf(o0 - m) + expf(o1 - m));
        out[d] = make_float2(o0 - ls, o1 - ls);
    }
}

extern "C" void kernel_launch(void* const* d_in, const int* in_sizes, int n_in,
                              void* d_out, int out_size, void* d_ws, size_t ws_size,
                              hipStream_t stream) {
    const float* x  = (const float*)d_in[0];
    const int*   ei = (const int*)d_in[1];     // int32 [2, E]
    const float* W1 = (const float*)d_in[2];
    const float* b1 = (const float*)d_in[3];
    const float* W2 = (const float*)d_in[4];
    const float* b2 = (const float*)d_in[5];

    const int n = in_sizes[0];                 // 100000
    const int E = in_sizes[1] / 2;             // 3200000
    const int* src = ei;
    const int* dst = ei + E;

    const int nbuck = (n + NPB - 1) >> NBSH;   // 782 (<= PBS for the scan)
    const int epb   = (E + NPART - 1) / NPART; // 12500 (<= PBS*EPT)

    // Workspace layout (~32 MB).
    char* ws = (char*)d_ws;
    size_t off = 0;
    auto take = [&](size_t bytes) { char* p = ws + off; off += (bytes + 7) & ~(size_t)7; return p; };
    int*      offT   = (int*)take((size_t)NPART * nbuck * 4);     // 0.8 MB
    unsigned* packed = (unsigned*)take((size_t)E * 4);            // 12.8 MB
    unsigned* sorted = (unsigned*)take((size_t)nbuck * CAP * 4);  // 16 MB
    int*      nstart = (int*)take((size_t)n * 4);
    int*      nend   = (int*)take((size_t)n * 4);
    float*    dis    = (float*)take((size_t)n * 4);
    float*    p1     = (float*)take((size_t)n * 4);
    float2*   p2     = (float2*)take((size_t)n * 8);

    const int gridAgg = ((size_t)n * LPN + ABS - 1) / ABS;        // 782

    k_part<<<NPART, PBS, 0, stream>>>(src, dst, E, epb, nbuck, offT, packed);
    k_csr <<<nbuck, CBS, 0, stream>>>(packed, offT, x, E, epb, nbuck, n,
                                      sorted, nstart, nend, dis, p1);
    k_agg1<<<gridAgg, ABS, 0, stream>>>(sorted, nstart, nend, dis, p1,
                                        W1, b1, W2, n, p2);
    k_agg2<<<gridAgg, ABS, 0, stream>>>(sorted, nstart, nend, dis, p2,
                                        b2, n, (float2*)d_out);
}

// Round 10
// 102.383 us; speedup vs baseline: 1.1616x; 1.0701x over previous
//
#include <hip/hip_runtime.h>

// GCN 2-layer for MI355X — two-level counting sort to per-node CSR, then
// atomic-free register-reduction aggregation.
// Round-10 changes: (1) k_part 512 blocks x 1024 thr, EPT=7 (2 blocks/CU,
// 32 waves/CU, half the serial work per block); (2) agg loops 2x-unrolled
// for MLP=2 (two independent L2 gathers in flight per lane).
//
// record: src (bits 0..16) | local_dst (bits 17..23), NPB=128

#define NPB    128      // nodes per bucket
#define NBSH   7
#define NPART  512      // partition blocks
#define PBS    1024     // k_part threads (>= nbuck for the scan)
#define EPT    7        // edges/thread in k_part (epb=6250 <= 7168)
#define CAP    5120     // max records per bucket (mean 4092, sd 64; +16 sd)
#define CBS    1024     // k_csr threads
#define ABS    256      // agg threads
#define LPN    4        // lanes per node in agg

// ---- level 1: block-major bucket sort (one kernel, no global scan) ----
__global__ __launch_bounds__(PBS) void k_part(
    const int* __restrict__ src, const int* __restrict__ dst,
    int E, int epb, int nbuck,
    int* __restrict__ offT, unsigned* __restrict__ packed)
{
    __shared__ int s_scan[PBS];
    __shared__ unsigned stage[PBS * EPT];
    const int b = blockIdx.x, t = threadIdx.x;
    const int lo = b * epb;
    int blockEdges = min(epb, E - lo); if (blockEdges < 0) blockEdges = 0;

    unsigned rec[EPT]; int bkt[EPT];
    s_scan[t] = 0;
    __syncthreads();
#pragma unroll
    for (int it = 0; it < EPT; ++it) {
        int idx = it * PBS + t;
        bkt[it] = -1; rec[it] = 0;
        if (idx < blockEdges) {
            int d = dst[lo + idx], s = src[lo + idx];
            rec[it] = (unsigned)s | ((unsigned)(d & (NPB - 1)) << 17);
            bkt[it] = d >> NBSH;
            atomicAdd(&s_scan[bkt[it]], 1);
        }
    }
    __syncthreads();
    int v = s_scan[t];
    for (int off = 1; off < PBS; off <<= 1) {
        __syncthreads();
        int a = (t >= off) ? s_scan[t - off] : 0;
        __syncthreads();
        s_scan[t] += a;
    }
    __syncthreads();
    int excl = s_scan[t] - v;
    __syncthreads();
    s_scan[t] = excl;                          // reuse as cursors
    if (t < nbuck) offT[(size_t)b * nbuck + t] = excl;
    __syncthreads();
#pragma unroll
    for (int it = 0; it < EPT; ++it)
        if (bkt[it] >= 0) {
            int pos = atomicAdd(&s_scan[bkt[it]], 1);
            stage[pos] = rec[it];
        }
    __syncthreads();
    for (int i = t; i < blockEdges; i += PBS)
        packed[(size_t)lo + i] = stage[i];
}

// ---- level 2: per-bucket node-level sort -> CSR + deg/dis/p1 fused ----
__global__ __launch_bounds__(CBS) void k_csr(
    const unsigned* __restrict__ packed, const int* __restrict__ offT,
    const float* __restrict__ x,
    int E, int epb, int nbuck, int n,
    unsigned* __restrict__ sorted, int* __restrict__ nstart, int* __restrict__ nend,
    float* __restrict__ dis, float* __restrict__ p1)
{
    __shared__ unsigned raw[CAP];
    __shared__ int offs[NPART], flen[NPART], fbase[NPART];
    __shared__ int cnt[NPB], cur[NPB];
    const int k = blockIdx.x, t = threadIdx.x;

    if (t < NPART) {
        int o = offT[(size_t)t * nbuck + k];
        int e = (k + 1 < nbuck) ? offT[(size_t)t * nbuck + k + 1]
                                : max(0, min(epb, E - t * epb));
        offs[t] = o; flen[t] = e - o;
        fbase[t] = e - o;
    }
    if (t < NPB) cnt[t] = 0;
    __syncthreads();
    // exclusive scan of fragment lengths -> fbase
    for (int off = 1; off < NPART; off <<= 1) {
        __syncthreads();
        int a = (t >= off && t < NPART) ? fbase[t - off] : 0;
        __syncthreads();
        if (t < NPART) fbase[t] += a;
    }
    __syncthreads();
    int bsize = min(fbase[NPART - 1], CAP);
    __syncthreads();
    if (t < NPART) fbase[t] -= flen[t];
    __syncthreads();
    // gather fragments into raw[]: 8 contiguous lanes per fragment
    // (avg fragment ~8 recs), 4 passes of 128 fragments each.
    for (int fb = 0; fb < NPART; fb += (CBS >> 3)) {
        int f = fb + (t >> 3);
        if (f < NPART) {
            const unsigned* pp = packed + (size_t)f * epb + offs[f];
            int base = fbase[f], len = flen[f];
            for (int i = (t & 7); i < len; i += 8) {
                int p = base + i;
                if (p < CAP) raw[p] = pp[i];
            }
        }
    }
    __syncthreads();
    // node-level count
    for (int i = t; i < bsize; i += CBS)
        atomicAdd(&cnt[raw[i] >> 17], 1);
    __syncthreads();
    // exclusive scan of cnt (in cur), keep cnt = deg
    if (t < NPB) cur[t] = cnt[t];
    for (int off = 1; off < NPB; off <<= 1) {
        __syncthreads();
        int a = (t >= off && t < NPB) ? cur[t - off] : 0;
        __syncthreads();
        if (t < NPB) cur[t] += a;
    }
    __syncthreads();
    if (t < NPB) {
        int deg = cnt[t];
        int excl = cur[t] - deg;
        cur[t] = excl;                         // cursor for scatter
        int d = k * NPB + t;
        if (d < n) {
            int st = k * CAP + excl;
            nstart[d] = st;
            nend[d]   = min(st + deg, (k + 1) * CAP);
            float r = rsqrtf((float)(deg + 1)); // +1 self-loop
            dis[d] = r;
            p1[d]  = x[d] * r;
        }
    }
    __syncthreads();
    // scatter into node-sorted order
    for (int i = t; i < bsize; i += CBS) {
        unsigned u = raw[i];
        int pos = k * CAP + atomicAdd(&cur[u >> 17], 1);
        sorted[pos] = u;
    }
}

// ---- layer 1: atomic-free segment reduce + fused MLP -> p2 ----
__global__ __launch_bounds__(ABS) void k_agg1(
    const unsigned* __restrict__ sorted,
    const int* __restrict__ nstart, const int* __restrict__ nend,
    const float* __restrict__ dis, const float* __restrict__ p1,
    const float* __restrict__ W1, const float* __restrict__ b1,
    const float* __restrict__ W2, int n, float2* __restrict__ p2)
{
    int gid = blockIdx.x * ABS + threadIdx.x;
    int d = gid >> 2, lane = gid & (LPN - 1);
    if (d >= n) return;
    int s0 = nstart[d], e0 = nend[d];
    float acc = 0.f;
    int i = s0 + lane;
    for (; i + LPN < e0; i += 2 * LPN) {       // MLP=2: two gathers in flight
        unsigned u1 = sorted[i];
        unsigned u2 = sorted[i + LPN];
        float g1 = __builtin_nontemporal_load(&p1[u1 & 0x1FFFFu]);
        float g2 = __builtin_nontemporal_load(&p1[u2 & 0x1FFFFu]);
        acc += g1 + g2;
    }
    if (i < e0) acc += __builtin_nontemporal_load(&p1[sorted[i] & 0x1FFFFu]);
    acc += __shfl_xor(acc, 1);
    acc += __shfl_xor(acc, 2);
    if (lane == 0) {
        float r   = dis[d];
        float agg = r * (acc + p1[d]);          // + self-loop
        float c0 = 0.f, c1 = 0.f;
#pragma unroll
        for (int j = 0; j < 16; ++j) {
            float h = fmaxf(fmaf(agg, W1[j], b1[j]), 0.f);
            c0 = fmaf(h, W2[2 * j],     c0);
            c1 = fmaf(h, W2[2 * j + 1], c1);
        }
        p2[d] = make_float2(c0 * r, c1 * r);    // prescaled by dis[src]
    }
}

// ---- layer 2: atomic-free segment reduce + fused log-softmax -> out ----
__global__ __launch_bounds__(ABS) void k_agg2(
    const unsigned* __restrict__ sorted,
    const int* __restrict__ nstart, const int* __restrict__ nend,
    const float* __restrict__ dis, const float2* __restrict__ p2,
    const float* __restrict__ b2, int n, float2* __restrict__ out)
{
    int gid = blockIdx.x * ABS + threadIdx.x;
    int d = gid >> 2, lane = gid & (LPN - 1);
    if (d >= n) return;
    int s0 = nstart[d], e0 = nend[d];
    const double* p2d = (const double*)p2;
    float c0 = 0.f, c1 = 0.f;
    int i = s0 + lane;
    for (; i + LPN < e0; i += 2 * LPN) {       // MLP=2
        unsigned u1 = sorted[i];
        unsigned u2 = sorted[i + LPN];
        double dv1 = __builtin_nontemporal_load(&p2d[u1 & 0x1FFFFu]);
        double dv2 = __builtin_nontemporal_load(&p2d[u2 & 0x1FFFFu]);
        float2 v1 = *(float2*)&dv1;
        float2 v2 = *(float2*)&dv2;
        c0 += v1.x + v2.x; c1 += v1.y + v2.y;
    }
    if (i < e0) {
        double dv = __builtin_nontemporal_load(&p2d[sorted[i] & 0x1FFFFu]);
        float2 v = *(float2*)&dv;
        c0 += v.x; c1 += v.y;
    }
    c0 += __shfl_xor(c0, 1);  c0 += __shfl_xor(c0, 2);
    c1 += __shfl_xor(c1, 1);  c1 += __shfl_xor(c1, 2);
    if (lane == 0) {
        float r = dis[d];
        float2 self = p2[d];
        float o0 = r * (c0 + self.x) + b2[0];
        float o1 = r * (c1 + self.y) + b2[1];
        float m  = fmaxf(o0, o1);
        float ls = m + logf(expf(o0 - m) + expf(o1 - m));
        out[d] = make_float2(o0 - ls, o1 - ls);
    }
}

extern "C" void kernel_launch(void* const* d_in, const int* in_sizes, int n_in,
                              void* d_out, int out_size, void* d_ws, size_t ws_size,
                              hipStream_t stream) {
    const float* x  = (const float*)d_in[0];
    const int*   ei = (const int*)d_in[1];     // int32 [2, E]
    const float* W1 = (const float*)d_in[2];
    const float* b1 = (const float*)d_in[3];
    const float* W2 = (const float*)d_in[4];
    const float* b2 = (const float*)d_in[5];

    const int n = in_sizes[0];                 // 100000
    const int E = in_sizes[1] / 2;             // 3200000
    const int* src = ei;
    const int* dst = ei + E;

    const int nbuck = (n + NPB - 1) >> NBSH;   // 782 (<= PBS for the scan)
    const int epb   = (E + NPART - 1) / NPART; // 6250 (<= PBS*EPT)

    // Workspace layout (~33 MB).
    char* ws = (char*)d_ws;
    size_t off = 0;
    auto take = [&](size_t bytes) { char* p = ws + off; off += (bytes + 7) & ~(size_t)7; return p; };
    int*      offT   = (int*)take((size_t)NPART * nbuck * 4);     // 1.6 MB
    unsigned* packed = (unsigned*)take((size_t)E * 4);            // 12.8 MB
    unsigned* sorted = (unsigned*)take((size_t)nbuck * CAP * 4);  // 16 MB
    int*      nstart = (int*)take((size_t)n * 4);
    int*      nend   = (int*)take((size_t)n * 4);
    float*    dis    = (float*)take((size_t)n * 4);
    float*    p1     = (float*)take((size_t)n * 4);
    float2*   p2     = (float2*)take((size_t)n * 8);

    const int gridAgg = ((size_t)n * LPN + ABS - 1) / ABS;        // 1563

    k_part<<<NPART, PBS, 0, stream>>>(src, dst, E, epb, nbuck, offT, packed);
    k_csr <<<nbuck, CBS, 0, stream>>>(packed, offT, x, E, epb, nbuck, n,
                                      sorted, nstart, nend, dis, p1);
    k_agg1<<<gridAgg, ABS, 0, stream>>>(sorted, nstart, nend, dis, p1,
                                        W1, b1, W2, n, p2);
    k_agg2<<<gridAgg, ABS, 0, stream>>>(sorted, nstart, nend, dis, p2,
                                        b2, n, (float2*)d_out);
}